// Round 4
// baseline (428.008 us; speedup 1.0000x reference)
//
#include <hip/hip_runtime.h>
#include <math.h>

#define R_TOT 8192
#define CORE  4915
#define SHELL 2457
#define FB    820
#define H     1024

// Device-global scratch (fully rewritten every launch before any read).
__device__ __align__(16) float g_pred1[R_TOT];
__device__ __align__(16) float g_s[R_TOT];
__device__ __align__(16) float g_gates[4 * H];
__device__ int g_done = 0;  // k_gates last-block counter; reset by last block

// LDS swizzle for the misaligned scalar path: i -> i + i/32 (2 lanes/bank = free).
__device__ __forceinline__ int swz(int i) { return i + (i >> 5); }
#define SWZ_SIZE(n) ((n) + (((n) - 1) >> 5))

__device__ __forceinline__ float waveReduce(float v) {
  #pragma unroll
  for (int off = 32; off; off >>= 1) v += __shfl_down(v, off, 64);
  return v;
}

__device__ __forceinline__ float sigm(float x) { return 1.f / (1.f + expf(-x)); }
__device__ __forceinline__ float dot4(float4 a, float4 b) {
  return a.x * b.x + a.y * b.y + a.z * b.z + a.w * b.w;
}

// ---- Pair misaligned path: rows wA,wB share 16B phase (guaranteed when
// wB = wA + 4*rowstride elements). x staged swizzled in LDS. 16 float4 loads
// in flight per wave; x reads shared between both rows.
__device__ __forceinline__ float2 dotRow2Sw(const float* __restrict__ wA,
                                            const float* __restrict__ wB,
                                            const float* __restrict__ xs,
                                            int N, int lane) {
  uintptr_t a = (uintptr_t)wA;
  int head = (int)(((16 - (a & 15)) & 15) >> 2);
  if (head > N) head = N;
  float a0 = 0.f, a1 = 0.f, a2 = 0.f, a3 = 0.f;
  float b0 = 0.f, b1 = 0.f, b2 = 0.f, b3 = 0.f;
  if (lane < head) {
    float xv = xs[swz(lane)];
    a0 += wA[lane] * xv; b0 += wB[lane] * xv;
  }
  int nC = (N - head) >> 2;
  const float4* va = (const float4*)(wA + head);
  const float4* vb = (const float4*)(wB + head);
  int c = lane;
  #define CH2(Ak, Bk, off, accA, accB) { int ii = i0 + (off);                 \
      float x0_ = xs[swz(ii)],     x1_ = xs[swz(ii + 1)],                     \
            x2_ = xs[swz(ii + 2)], x3_ = xs[swz(ii + 3)];                     \
      accA += Ak.x * x0_ + Ak.y * x1_ + Ak.z * x2_ + Ak.w * x3_;              \
      accB += Bk.x * x0_ + Bk.y * x1_ + Bk.z * x2_ + Bk.w * x3_; }
  for (; c + 448 < nC; c += 512) {
    float4 A0 = va[c],       A1 = va[c + 64],  A2 = va[c + 128], A3 = va[c + 192],
           A4 = va[c + 256], A5 = va[c + 320], A6 = va[c + 384], A7 = va[c + 448];
    float4 B0 = vb[c],       B1 = vb[c + 64],  B2 = vb[c + 128], B3 = vb[c + 192],
           B4 = vb[c + 256], B5 = vb[c + 320], B6 = vb[c + 384], B7 = vb[c + 448];
    int i0 = head + (c << 2);
    CH2(A0, B0, 0,    a0, b0) CH2(A1, B1, 256,  a1, b1)
    CH2(A2, B2, 512,  a2, b2) CH2(A3, B3, 768,  a3, b3)
    CH2(A4, B4, 1024, a0, b0) CH2(A5, B5, 1280, a1, b1)
    CH2(A6, B6, 1536, a2, b2) CH2(A7, B7, 1792, a3, b3)
  }
  for (; c + 192 < nC; c += 256) {
    float4 A0 = va[c], A1 = va[c + 64], A2 = va[c + 128], A3 = va[c + 192];
    float4 B0 = vb[c], B1 = vb[c + 64], B2 = vb[c + 128], B3 = vb[c + 192];
    int i0 = head + (c << 2);
    CH2(A0, B0, 0,   a0, b0) CH2(A1, B1, 256, a1, b1)
    CH2(A2, B2, 512, a2, b2) CH2(A3, B3, 768, a3, b3)
  }
  for (; c < nC; c += 64) {
    float4 A0 = va[c], B0 = vb[c];
    int i0 = head + (c << 2);
    CH2(A0, B0, 0, a0, b0)
  }
  #undef CH2
  for (int i = head + (nC << 2) + lane; i < N; i += 64) {
    float xv = xs[swz(i)];
    a2 += wA[i] * xv; b2 += wB[i] * xv;
  }
  return make_float2((a0 + a1) + (a2 + a3), (b0 + b1) + (b2 + b3));
}

// ---- Pair aligned path: both rows 16B-aligned, xs as plain float4 in LDS ----
__device__ __forceinline__ float2 dotRow2Al(const float4* __restrict__ wa,
                                            const float4* __restrict__ wb,
                                            const float4* __restrict__ xs4,
                                            int nC, int lane) {
  float a0 = 0.f, a1 = 0.f, a2 = 0.f, a3 = 0.f;
  float b0 = 0.f, b1 = 0.f, b2 = 0.f, b3 = 0.f;
  int c = lane;
  for (; c + 448 < nC; c += 512) {
    float4 A0 = wa[c],       A1 = wa[c + 64],  A2 = wa[c + 128], A3 = wa[c + 192],
           A4 = wa[c + 256], A5 = wa[c + 320], A6 = wa[c + 384], A7 = wa[c + 448];
    float4 B0 = wb[c],       B1 = wb[c + 64],  B2 = wb[c + 128], B3 = wb[c + 192],
           B4 = wb[c + 256], B5 = wb[c + 320], B6 = wb[c + 384], B7 = wb[c + 448];
    float4 X0 = xs4[c],       X1 = xs4[c + 64],  X2 = xs4[c + 128], X3 = xs4[c + 192],
           X4 = xs4[c + 256], X5 = xs4[c + 320], X6 = xs4[c + 384], X7 = xs4[c + 448];
    a0 += dot4(A0, X0); b0 += dot4(B0, X0); a1 += dot4(A1, X1); b1 += dot4(B1, X1);
    a2 += dot4(A2, X2); b2 += dot4(B2, X2); a3 += dot4(A3, X3); b3 += dot4(B3, X3);
    a0 += dot4(A4, X4); b0 += dot4(B4, X4); a1 += dot4(A5, X5); b1 += dot4(B5, X5);
    a2 += dot4(A6, X6); b2 += dot4(B6, X6); a3 += dot4(A7, X7); b3 += dot4(B7, X7);
  }
  for (; c + 192 < nC; c += 256) {
    float4 A0 = wa[c], A1 = wa[c + 64], A2 = wa[c + 128], A3 = wa[c + 192];
    float4 B0 = wb[c], B1 = wb[c + 64], B2 = wb[c + 128], B3 = wb[c + 192];
    float4 X0 = xs4[c], X1 = xs4[c + 64], X2 = xs4[c + 128], X3 = xs4[c + 192];
    a0 += dot4(A0, X0); b0 += dot4(B0, X0); a1 += dot4(A1, X1); b1 += dot4(B1, X1);
    a2 += dot4(A2, X2); b2 += dot4(B2, X2); a3 += dot4(A3, X3); b3 += dot4(B3, X3);
  }
  for (; c < nC; c += 64) {
    float4 A0 = wa[c], B0 = wb[c], X0 = xs4[c];
    a0 += dot4(A0, X0); b0 += dot4(B0, X0);
  }
  return make_float2((a0 + a1) + (a2 + a3), (b0 + b1) + (b2 + b3));
}

// ---- Single-row tails (partial last blocks only; perf-irrelevant) ----
__device__ __forceinline__ float dotRowSw(const float* __restrict__ w,
                                          const float* __restrict__ xs,
                                          int N, int lane) {
  uintptr_t a = (uintptr_t)w;
  int head = (int)(((16 - (a & 15)) & 15) >> 2);
  if (head > N) head = N;
  float s0 = 0.f, s1 = 0.f, s2 = 0.f, s3 = 0.f;
  if (lane < head) s0 += w[lane] * xs[swz(lane)];
  int nC = (N - head) >> 2;
  const float4* wv = (const float4*)(w + head);
  int c = lane;
  for (; c + 192 < nC; c += 256) {
    float4 v0 = wv[c], v1 = wv[c + 64], v2 = wv[c + 128], v3 = wv[c + 192];
    int i0 = head + (c << 2);
    s0 += v0.x*xs[swz(i0    )] + v0.y*xs[swz(i0+  1)] + v0.z*xs[swz(i0+  2)] + v0.w*xs[swz(i0+  3)];
    s1 += v1.x*xs[swz(i0+256)] + v1.y*xs[swz(i0+257)] + v1.z*xs[swz(i0+258)] + v1.w*xs[swz(i0+259)];
    s2 += v2.x*xs[swz(i0+512)] + v2.y*xs[swz(i0+513)] + v2.z*xs[swz(i0+514)] + v2.w*xs[swz(i0+515)];
    s3 += v3.x*xs[swz(i0+768)] + v3.y*xs[swz(i0+769)] + v3.z*xs[swz(i0+770)] + v3.w*xs[swz(i0+771)];
  }
  for (; c < nC; c += 64) {
    float4 v = wv[c];
    int i0 = head + (c << 2);
    s1 += v.x*xs[swz(i0)] + v.y*xs[swz(i0+1)] + v.z*xs[swz(i0+2)] + v.w*xs[swz(i0+3)];
  }
  for (int i = head + (nC << 2) + lane; i < N; i += 64)
    s2 += w[i] * xs[swz(i)];
  return (s0 + s1) + (s2 + s3);
}

__device__ __forceinline__ float dotRowAl(const float4* __restrict__ wv,
                                          const float4* __restrict__ xs4,
                                          int nC, int lane) {
  float s0 = 0.f, s1 = 0.f, s2 = 0.f, s3 = 0.f;
  int c = lane;
  for (; c + 192 < nC; c += 256) {
    float4 v0 = wv[c], v1 = wv[c + 64], v2 = wv[c + 128], v3 = wv[c + 192];
    s0 += dot4(v0, xs4[c]);       s1 += dot4(v1, xs4[c + 64]);
    s2 += dot4(v2, xs4[c + 128]); s3 += dot4(v3, xs4[c + 192]);
  }
  for (; c < nC; c += 64) s0 += dot4(wv[c], xs4[c]);
  return (s0 + s1) + (s2 + s3);
}

__device__ __forceinline__ void s_update(int i, float pred,
                                         const float* __restrict__ state,
                                         const float* __restrict__ omega,
                                         const float* __restrict__ gamma,
                                         float dopa, float* __restrict__ dout) {
  float old = state[i];
  float s1 = 0.9f * old + 0.1f * pred;
  float s2 = s1 + 0.1f * (omega[i] * s1 - gamma[i] * tanhf(s1));
  float s3 = dopa * s2;
  g_s[i] = s3;
  dout[1 + i] = s3;  // s occupies output elements [1, 1+R_TOT)
}

// ---------------- Stage 1: core/shell/fb matvecs + W_hh@h partial gates -----
// 8 rows per block, wave w owns rows (b*8+w, b*8+w+4): same 16B phase.
#define NB1_CORE8  ((CORE + 7) / 8)    // 615
#define NB1_SHELL8 ((SHELL + 7) / 8)   // 308
#define NB1_WHH8   (4 * H / 8)         // 512
#define NB1_FB8    ((FB + 7) / 8)      // 103
#define NB1_TOT    (NB1_CORE8 + NB1_SHELL8 + NB1_WHH8 + NB1_FB8)

__global__ __launch_bounds__(256, 4) void k_stage1(
    const float* __restrict__ state, const float* __restrict__ Wcore,
    const float* __restrict__ Wshell, const float* __restrict__ Wfb,
    const float* __restrict__ Win, const float* __restrict__ xin,
    const float* __restrict__ Whh, const float* __restrict__ hin) {
  __shared__ __align__(16) float xs[SWZ_SIZE(CORE)];  // 20,272 B
  int b = blockIdx.x, tid = threadIdx.x, wave = tid >> 6, lane = tid & 63;
  if (b < NB1_CORE8) {
    for (int i = tid; i < CORE; i += 256) xs[swz(i)] = state[i];
    __syncthreads();
    int rA = b * 8 + wave, rB = rA + 4;
    if (rA >= CORE) return;
    float x0 = xin[0];
    if (rB < CORE) {
      float2 d = dotRow2Sw(Wcore + (size_t)rA * CORE, Wcore + (size_t)rB * CORE,
                           xs, CORE, lane);
      d.x = waveReduce(d.x); d.y = waveReduce(d.y);
      if (lane == 0) {
        g_pred1[rA] = tanhf(d.x + Win[rA] * x0);
        g_pred1[rB] = tanhf(d.y + Win[rB] * x0);
      }
    } else {
      float s = waveReduce(dotRowSw(Wcore + (size_t)rA * CORE, xs, CORE, lane));
      if (lane == 0) g_pred1[rA] = tanhf(s + Win[rA] * x0);
    }
  } else if (b < NB1_CORE8 + NB1_SHELL8) {
    for (int i = tid; i < SHELL; i += 256) xs[swz(i)] = state[CORE + i];
    __syncthreads();
    int rA = (b - NB1_CORE8) * 8 + wave, rB = rA + 4;
    if (rA >= SHELL) return;
    if (rB < SHELL) {
      float2 d = dotRow2Sw(Wshell + (size_t)rA * SHELL, Wshell + (size_t)rB * SHELL,
                           xs, SHELL, lane);
      d.x = waveReduce(d.x); d.y = waveReduce(d.y);
      if (lane == 0) {
        g_pred1[CORE + rA] = tanhf(d.x);
        g_pred1[CORE + rB] = tanhf(d.y);
      }
    } else {
      float s = waveReduce(dotRowSw(Wshell + (size_t)rA * SHELL, xs, SHELL, lane));
      if (lane == 0) g_pred1[CORE + rA] = tanhf(s);
    }
  } else if (b < NB1_CORE8 + NB1_SHELL8 + NB1_WHH8) {
    // W_hh @ h: all rows 16B-aligned (stride H). Raw partials into g_gates.
    float4* xs4 = (float4*)xs;
    const float4* h4 = (const float4*)hin;
    for (int i = tid; i < H / 4; i += 256) xs4[i] = h4[i];
    __syncthreads();
    int rA = (b - NB1_CORE8 - NB1_SHELL8) * 8 + wave, rB = rA + 4;  // < 4096
    float2 d = dotRow2Al((const float4*)(Whh + (size_t)rA * H),
                         (const float4*)(Whh + (size_t)rB * H), xs4, H / 4, lane);
    d.x = waveReduce(d.x); d.y = waveReduce(d.y);
    if (lane == 0) { g_gates[rA] = d.x; g_gates[rB] = d.y; }
  } else {
    // FB: rows 16B-aligned (FB%4==0); state+CORE+SHELL is 16B-aligned (7372%4==0).
    float4* xs4 = (float4*)xs;
    const float4* f4 = (const float4*)(state + CORE + SHELL);
    for (int i = tid; i < FB / 4; i += 256) xs4[i] = f4[i];
    __syncthreads();
    int rA = (b - NB1_CORE8 - NB1_SHELL8 - NB1_WHH8) * 8 + wave, rB = rA + 4;
    if (rA >= FB) return;
    if (rB < FB) {
      float2 d = dotRow2Al((const float4*)(Wfb + (size_t)rA * FB),
                           (const float4*)(Wfb + (size_t)rB * FB), xs4, FB / 4, lane);
      d.x = waveReduce(d.x); d.y = waveReduce(d.y);
      if (lane == 0) {
        g_pred1[CORE + SHELL + rA] = tanhf(d.x);
        g_pred1[CORE + SHELL + rB] = tanhf(d.y);
      }
    } else {
      float s = waveReduce(dotRowAl((const float4*)(Wfb + (size_t)rA * FB),
                                    xs4, FB / 4, lane));
      if (lane == 0) g_pred1[CORE + SHELL + rA] = tanhf(s);
    }
  }
}

// ---------------- Stage 2: core cross-terms + full s update -----------------
#define NB2_CORE8 ((CORE + 7) / 8)           // 615
#define NB2_EW    ((SHELL + FB + 255) / 256) // 13

__global__ __launch_bounds__(256, 4) void k_stage2(
    const float* __restrict__ state,
    const float* __restrict__ Wsc, const float* __restrict__ Wfc,
    const float* __restrict__ omega, const float* __restrict__ gamma,
    const float* __restrict__ dopamine, float* __restrict__ dout) {
  __shared__ __align__(16) float  xsS[SWZ_SIZE(SHELL)];  // shell preds, swizzled
  __shared__ __align__(16) float4 xsF[FB / 4];           // fb preds, aligned
  float dopa = dopamine[0];
  int b = blockIdx.x, tid = threadIdx.x;
  if (b < NB2_CORE8) {
    for (int i = tid; i < SHELL; i += 256) xsS[swz(i)] = g_pred1[CORE + i];
    const float4* f4 = (const float4*)(g_pred1 + CORE + SHELL);
    for (int i = tid; i < FB / 4; i += 256) xsF[i] = f4[i];
    __syncthreads();
    int wave = tid >> 6, lane = tid & 63;
    int rA = b * 8 + wave, rB = rA + 4;
    if (rA >= CORE) return;
    if (rB < CORE) {
      float2 d1 = dotRow2Sw(Wsc + (size_t)rA * SHELL, Wsc + (size_t)rB * SHELL,
                            xsS, SHELL, lane);
      float2 d2 = dotRow2Al((const float4*)(Wfc + (size_t)rA * FB),
                            (const float4*)(Wfc + (size_t)rB * FB), xsF, FB / 4, lane);
      d1.x = waveReduce(d1.x); d1.y = waveReduce(d1.y);
      d2.x = waveReduce(d2.x); d2.y = waveReduce(d2.y);
      if (lane == 0) {
        s_update(rA, g_pred1[rA] + tanhf(d1.x) + tanhf(d2.x), state, omega, gamma, dopa, dout);
        s_update(rB, g_pred1[rB] + tanhf(d1.y) + tanhf(d2.y), state, omega, gamma, dopa, dout);
      }
    } else {
      float d1 = waveReduce(dotRowSw(Wsc + (size_t)rA * SHELL, xsS, SHELL, lane));
      float d2 = waveReduce(dotRowAl((const float4*)(Wfc + (size_t)rA * FB),
                                     xsF, FB / 4, lane));
      if (lane == 0)
        s_update(rA, g_pred1[rA] + tanhf(d1) + tanhf(d2), state, omega, gamma, dopa, dout);
    }
  } else {
    int i = CORE + (b - NB2_CORE8) * 256 + tid;
    if (i < R_TOT) s_update(i, g_pred1[i], state, omega, gamma, dopa, dout);
  }
}

// -------- Stage 3: gates += W_ih @ s + biases; last block runs the LSTM -----
#define NBG (4 * H / 8)  // 512 blocks, 8 rows each

__global__ __launch_bounds__(256, 4) void k_gates(
    const float* __restrict__ Wih,
    const float* __restrict__ bih, const float* __restrict__ bhh,
    const float* __restrict__ cin, const float* __restrict__ Wout,
    const float* __restrict__ bout, float* __restrict__ dout) {
  __shared__ __align__(16) float4 xs4[R_TOT / 4];  // 32,768 B
  __shared__ float red[4];
  __shared__ int s_last;
  int tid = threadIdx.x, wave = tid >> 6, lane = tid & 63;
  const float4* s4 = (const float4*)g_s;
  for (int i = tid; i < R_TOT / 4; i += 256) xs4[i] = s4[i];
  __syncthreads();
  int rA = blockIdx.x * 8 + wave, rB = rA + 4;  // all < 4096
  float2 d = dotRow2Al((const float4*)(Wih + (size_t)rA * R_TOT),
                       (const float4*)(Wih + (size_t)rB * R_TOT),
                       xs4, R_TOT / 4, lane);
  d.x = waveReduce(d.x); d.y = waveReduce(d.y);
  if (lane == 0) {
    g_gates[rA] += d.x + bih[rA] + bhh[rA];
    g_gates[rB] += d.y + bih[rB] + bhh[rB];
  }
  // Last-block fold of the LSTM elementwise + output dot (saves a launch).
  __threadfence();
  __syncthreads();
  if (tid == 0) {
    int prev = atomicAdd(&g_done, 1);
    s_last = (prev == (int)gridDim.x - 1);
    if (s_last) atomicExch(&g_done, 0);  // reset for next launch
  }
  __syncthreads();
  if (!s_last) return;
  __threadfence();  // acquire: see all blocks' g_gates stores
  float acc = 0.f;
  for (int j = tid; j < H; j += 256) {
    float ig = g_gates[j], fg = g_gates[H + j];
    float gg = g_gates[2 * H + j], og = g_gates[3 * H + j];
    float cc = cin[j];
    float cn = sigm(fg) * cc + sigm(ig) * tanhf(gg);
    float hn = sigm(og) * tanhf(cn);
    dout[1 + R_TOT + j] = hn;
    dout[1 + R_TOT + H + j] = cn;
    acc += Wout[j] * hn;
  }
  acc = waveReduce(acc);
  if (lane == 0) red[wave] = acc;
  __syncthreads();
  if (tid == 0) dout[0] = red[0] + red[1] + red[2] + red[3] + bout[0];
}

extern "C" void kernel_launch(void* const* d_in, const int* in_sizes, int n_in,
                              void* d_out, int out_size, void* d_ws, size_t ws_size,
                              hipStream_t stream) {
  // Map inputs by element-count fingerprint (confirmed f32).
  const float *x = 0, *state = 0, *h = 0, *c = 0, *Win = 0, *Wcore = 0, *Wshell = 0,
              *Wfb = 0, *Wsc = 0, *Wfc = 0, *dopa = 0, *omega = 0, *gamma = 0,
              *Wih = 0, *Whh = 0, *bih = 0, *bhh = 0, *Wout = 0, *bout = 0;
  int n1 = 0, n1024 = 0, n8192 = 0, n4096 = 0;
  for (int i = 0; i < n_in; ++i) {
    const float* p = (const float*)d_in[i];
    switch (in_sizes[i]) {
      case 24157225: Wcore = p; break;            // CORE^2
      case 6036849:  Wshell = p; break;           // SHELL^2
      case 672400:   Wfb = p; break;              // FB^2
      case 12076155: Wsc = p; break;              // CORE*SHELL
      case 4030300:  Wfc = p; break;              // CORE*FB
      case 33554432: Wih = p; break;              // 4H*R
      case 4194304:  Whh = p; break;              // 4H*H
      case 1:    { if (n1 == 0) x = p; else if (n1 == 1) dopa = p; else bout = p; n1++; } break;
      case 1024: { if (n1024 == 0) h = p; else if (n1024 == 1) c = p; else Wout = p; n1024++; } break;
      case 8192: { if (n8192 == 0) state = p; else if (n8192 == 1) Win = p;
                   else if (n8192 == 2) omega = p; else gamma = p; n8192++; } break;
      case 4096: { if (n4096 == 0) bih = p; else bhh = p; n4096++; } break;
      default: break;
    }
  }
  float* dout = (float*)d_out;

  k_stage1<<<NB1_TOT, 256, 0, stream>>>(state, Wcore, Wshell, Wfb, Win, x, Whh, h);
  k_stage2<<<NB2_CORE8 + NB2_EW, 256, 0, stream>>>(state, Wsc, Wfc, omega, gamma, dopa, dout);
  k_gates<<<NBG, 256, 0, stream>>>(Wih, bih, bhh, c, Wout, bout, dout);
}

// Round 5
// 365.621 us; speedup vs baseline: 1.1706x; 1.1706x over previous
//
#include <hip/hip_runtime.h>
#include <math.h>

#define R_TOT 8192
#define CORE  4915
#define SHELL 2457
#define FB    820
#define H     1024

// Device-global scratch (fully rewritten every launch before any read).
__device__ __align__(16) float g_pred1[R_TOT];
__device__ __align__(16) float g_s[R_TOT];
__device__ __align__(16) float g_gates[4 * H];      // Whh@h + biases (stage1)
__device__ __align__(16) float g_gpart[4][4 * H];   // W_ih K-chunk partials

__device__ __forceinline__ float waveReduce(float v) {
  #pragma unroll
  for (int off = 32; off; off >>= 1) v += __shfl_down(v, off, 64);
  return v;
}

__device__ __forceinline__ float sigm(float x) { return 1.f / (1.f + expf(-x)); }
__device__ __forceinline__ float dot4(float4 a, float4 b) {
  return a.x * b.x + a.y * b.y + a.z * b.z + a.w * b.w;
}

// ---- Misaligned-row path: w 4B-aligned (arbitrary 16B phase), xs plain LDS.
// x8/x4/x1 tiers; ~50 VGPR so it fits the 64-VGPR budget of 32 waves/CU.
__device__ __forceinline__ float dotRowSw(const float* __restrict__ w,
                                          const float* __restrict__ xs,
                                          int N, int lane) {
  uintptr_t a = (uintptr_t)w;
  int head = (int)(((16 - (a & 15)) & 15) >> 2);  // elements until 16B aligned
  if (head > N) head = N;
  float s0 = 0.f, s1 = 0.f, s2 = 0.f, s3 = 0.f;
  if (lane < head) s0 += w[lane] * xs[lane];
  int nC = (N - head) >> 2;
  const float4* wv = (const float4*)(w + head);
  int c = lane;
  for (; c + 448 < nC; c += 512) {
    float4 v0 = wv[c],       v1 = wv[c + 64],  v2 = wv[c + 128], v3 = wv[c + 192],
           v4 = wv[c + 256], v5 = wv[c + 320], v6 = wv[c + 384], v7 = wv[c + 448];
    int i0 = head + (c << 2);
    s0 += v0.x*xs[i0     ] + v0.y*xs[i0+   1] + v0.z*xs[i0+   2] + v0.w*xs[i0+   3];
    s1 += v1.x*xs[i0+ 256] + v1.y*xs[i0+ 257] + v1.z*xs[i0+ 258] + v1.w*xs[i0+ 259];
    s2 += v2.x*xs[i0+ 512] + v2.y*xs[i0+ 513] + v2.z*xs[i0+ 514] + v2.w*xs[i0+ 515];
    s3 += v3.x*xs[i0+ 768] + v3.y*xs[i0+ 769] + v3.z*xs[i0+ 770] + v3.w*xs[i0+ 771];
    s0 += v4.x*xs[i0+1024] + v4.y*xs[i0+1025] + v4.z*xs[i0+1026] + v4.w*xs[i0+1027];
    s1 += v5.x*xs[i0+1280] + v5.y*xs[i0+1281] + v5.z*xs[i0+1282] + v5.w*xs[i0+1283];
    s2 += v6.x*xs[i0+1536] + v6.y*xs[i0+1537] + v6.z*xs[i0+1538] + v6.w*xs[i0+1539];
    s3 += v7.x*xs[i0+1792] + v7.y*xs[i0+1793] + v7.z*xs[i0+1794] + v7.w*xs[i0+1795];
  }
  for (; c + 192 < nC; c += 256) {
    float4 v0 = wv[c], v1 = wv[c + 64], v2 = wv[c + 128], v3 = wv[c + 192];
    int i0 = head + (c << 2);
    s0 += v0.x*xs[i0    ] + v0.y*xs[i0+  1] + v0.z*xs[i0+  2] + v0.w*xs[i0+  3];
    s1 += v1.x*xs[i0+256] + v1.y*xs[i0+257] + v1.z*xs[i0+258] + v1.w*xs[i0+259];
    s2 += v2.x*xs[i0+512] + v2.y*xs[i0+513] + v2.z*xs[i0+514] + v2.w*xs[i0+515];
    s3 += v3.x*xs[i0+768] + v3.y*xs[i0+769] + v3.z*xs[i0+770] + v3.w*xs[i0+771];
  }
  for (; c < nC; c += 64) {
    float4 v = wv[c];
    int i0 = head + (c << 2);
    s1 += v.x*xs[i0] + v.y*xs[i0+1] + v.z*xs[i0+2] + v.w*xs[i0+3];
  }
  for (int i = head + (nC << 2) + lane; i < N; i += 64)
    s2 += w[i] * xs[i];
  return (s0 + s1) + (s2 + s3);
}

// ---- Aligned-row path: w 16B-aligned, xs as float4 LDS (ds_read_b128) ----
__device__ __forceinline__ float dotRowAl(const float4* __restrict__ wv,
                                          const float4* __restrict__ xs4,
                                          int nC, int lane) {
  float s0 = 0.f, s1 = 0.f, s2 = 0.f, s3 = 0.f;
  int c = lane;
  for (; c + 448 < nC; c += 512) {
    float4 v0 = wv[c],       v1 = wv[c + 64],  v2 = wv[c + 128], v3 = wv[c + 192],
           v4 = wv[c + 256], v5 = wv[c + 320], v6 = wv[c + 384], v7 = wv[c + 448];
    s0 += dot4(v0, xs4[c      ]); s1 += dot4(v1, xs4[c + 64 ]);
    s2 += dot4(v2, xs4[c + 128]); s3 += dot4(v3, xs4[c + 192]);
    s0 += dot4(v4, xs4[c + 256]); s1 += dot4(v5, xs4[c + 320]);
    s2 += dot4(v6, xs4[c + 384]); s3 += dot4(v7, xs4[c + 448]);
  }
  for (; c + 192 < nC; c += 256) {
    float4 v0 = wv[c], v1 = wv[c + 64], v2 = wv[c + 128], v3 = wv[c + 192];
    s0 += dot4(v0, xs4[c]);       s1 += dot4(v1, xs4[c + 64]);
    s2 += dot4(v2, xs4[c + 128]); s3 += dot4(v3, xs4[c + 192]);
  }
  for (; c < nC; c += 64) s0 += dot4(wv[c], xs4[c]);
  return (s0 + s1) + (s2 + s3);
}

__device__ __forceinline__ void s_update(int i, float pred,
                                         const float* __restrict__ state,
                                         const float* __restrict__ omega,
                                         const float* __restrict__ gamma,
                                         float dopa, float* __restrict__ dout) {
  float old = state[i];
  float s1 = 0.9f * old + 0.1f * pred;
  float s2 = s1 + 0.1f * (omega[i] * s1 - gamma[i] * tanhf(s1));
  float s3 = dopa * s2;
  g_s[i] = s3;
  dout[1 + i] = s3;  // s occupies output elements [1, 1+R_TOT)
}

// ---------------- Stage 1: core/shell/fb matvecs + W_hh@h gates base --------
// 4 rows per block, 1 row per wave. LDS = plain float[CORE] (19,660 B) so
// 8 blocks/CU fit; (256,8) -> 32 waves/CU (the round-4 lesson: occupancy,
// not per-wave unroll depth, sets the latency-bound streaming rate).
#define NB1_CORE  ((CORE  + 3) / 4)   // 1229
#define NB1_SHELL ((SHELL + 3) / 4)   // 615
#define NB1_WHH   (4 * H / 4)         // 1024
#define NB1_FB    ((FB    + 3) / 4)   // 205
#define NB1_TOT   (NB1_CORE + NB1_SHELL + NB1_WHH + NB1_FB)

__global__ __launch_bounds__(256, 8) void k_stage1(
    const float* __restrict__ state, const float* __restrict__ Wcore,
    const float* __restrict__ Wshell, const float* __restrict__ Wfb,
    const float* __restrict__ Win, const float* __restrict__ xin,
    const float* __restrict__ Whh, const float* __restrict__ hin,
    const float* __restrict__ bih, const float* __restrict__ bhh) {
  __shared__ __align__(16) float xs[CORE];  // 19,660 B -> 8 blocks/CU
  int b = blockIdx.x, tid = threadIdx.x, wave = tid >> 6, lane = tid & 63;
  if (b < NB1_CORE) {
    for (int i = tid; i < CORE; i += 256) xs[i] = state[i];
    __syncthreads();
    int r = b * 4 + wave;
    if (r >= CORE) return;
    float s = waveReduce(dotRowSw(Wcore + (size_t)r * CORE, xs, CORE, lane));
    if (lane == 0) g_pred1[r] = tanhf(s + Win[r] * xin[0]);
  } else if (b < NB1_CORE + NB1_SHELL) {
    for (int i = tid; i < SHELL; i += 256) xs[i] = state[CORE + i];
    __syncthreads();
    int r = (b - NB1_CORE) * 4 + wave;
    if (r >= SHELL) return;
    float s = waveReduce(dotRowSw(Wshell + (size_t)r * SHELL, xs, SHELL, lane));
    if (lane == 0) g_pred1[CORE + r] = tanhf(s);
  } else if (b < NB1_CORE + NB1_SHELL + NB1_WHH) {
    // W_hh @ h: rows 16B-aligned (stride H). Write gates base = dot + biases.
    float4* xs4 = (float4*)xs;
    const float4* h4 = (const float4*)hin;
    for (int i = tid; i < H / 4; i += 256) xs4[i] = h4[i];
    __syncthreads();
    int r = (b - NB1_CORE - NB1_SHELL) * 4 + wave;  // < 4096 always
    float s = waveReduce(dotRowAl((const float4*)(Whh + (size_t)r * H),
                                  xs4, H / 4, lane));
    if (lane == 0) g_gates[r] = s + bih[r] + bhh[r];
  } else {
    // FB: rows 16B-aligned (FB%4==0); state+CORE+SHELL is 16B-aligned.
    float4* xs4 = (float4*)xs;
    const float4* f4 = (const float4*)(state + CORE + SHELL);
    for (int i = tid; i < FB / 4; i += 256) xs4[i] = f4[i];
    __syncthreads();
    int r = (b - NB1_CORE - NB1_SHELL - NB1_WHH) * 4 + wave;
    if (r >= FB) return;
    float s = waveReduce(dotRowAl((const float4*)(Wfb + (size_t)r * FB),
                                  xs4, FB / 4, lane));
    if (lane == 0) g_pred1[CORE + SHELL + r] = tanhf(s);
  }
}

// ---------------- Stage 2: core cross-terms + full s update -----------------
#define NB2_CORE ((CORE + 3) / 4)            // 1229
#define NB2_EW   ((SHELL + FB + 255) / 256)  // 13

__global__ __launch_bounds__(256, 8) void k_stage2(
    const float* __restrict__ state,
    const float* __restrict__ Wsc, const float* __restrict__ Wfc,
    const float* __restrict__ omega, const float* __restrict__ gamma,
    const float* __restrict__ dopamine, float* __restrict__ dout) {
  __shared__ __align__(16) float  xsS[SHELL];    // 9,828 B
  __shared__ __align__(16) float4 xsF[FB / 4];   // 3,280 B
  float dopa = dopamine[0];
  int b = blockIdx.x, tid = threadIdx.x;
  if (b < NB2_CORE) {
    for (int i = tid; i < SHELL; i += 256) xsS[i] = g_pred1[CORE + i];
    const float4* f4 = (const float4*)(g_pred1 + CORE + SHELL);  // 7372%4==0
    for (int i = tid; i < FB / 4; i += 256) xsF[i] = f4[i];
    __syncthreads();
    int wave = tid >> 6, lane = tid & 63;
    int r = b * 4 + wave;
    if (r >= CORE) return;
    float d1 = waveReduce(dotRowSw(Wsc + (size_t)r * SHELL, xsS, SHELL, lane));
    float d2 = waveReduce(dotRowAl((const float4*)(Wfc + (size_t)r * FB),
                                   xsF, FB / 4, lane));
    if (lane == 0) {
      float pred = g_pred1[r] + tanhf(d1) + tanhf(d2);
      s_update(r, pred, state, omega, gamma, dopa, dout);
    }
  } else {
    int i = CORE + (b - NB2_CORE) * 256 + tid;
    if (i < R_TOT) s_update(i, g_pred1[i], state, omega, gamma, dopa, dout);
  }
}

// -------- Stage 3: W_ih @ s, K-split by 4 for occupancy ---------------------
// Block b: chunk k = b&3 (2048 elems), rows (b>>2)*4 + wave. Each lane holds
// exactly 8 float4 of W (straight-line, all 8 global loads in flight).
// 8 KB LDS + (256,8) -> 32 waves/CU, 4x round-4's residency. Partials go to
// g_gpart via plain stores (NO atomics: same-address atomics serialize ~30ns/op).
#define GCH   4
#define GCHN  (R_TOT / GCH)       // 2048 elems
#define GCHV  (GCHN / 4)          // 512 float4
#define NBG   (4 * H / 4 * GCH)   // 4096 blocks

__global__ __launch_bounds__(256, 8) void k_gates(const float* __restrict__ Wih) {
  __shared__ __align__(16) float4 xs4[GCHV];  // 8,192 B
  int b = blockIdx.x, tid = threadIdx.x, wave = tid >> 6, lane = tid & 63;
  int k = b & (GCH - 1);
  int r = ((b >> 2) << 2) + wave;  // < 4096 always
  const float4* s4 = (const float4*)g_s + k * GCHV;
  for (int i = tid; i < GCHV; i += 256) xs4[i] = s4[i];
  __syncthreads();
  const float4* wv = (const float4*)(Wih + (size_t)r * R_TOT) + k * GCHV;
  float4 A0 = wv[lane      ], A1 = wv[lane +  64], A2 = wv[lane + 128],
         A3 = wv[lane + 192], A4 = wv[lane + 256], A5 = wv[lane + 320],
         A6 = wv[lane + 384], A7 = wv[lane + 448];
  float s0 = dot4(A0, xs4[lane      ]) + dot4(A1, xs4[lane +  64]);
  float s1 = dot4(A2, xs4[lane + 128]) + dot4(A3, xs4[lane + 192]);
  float s2 = dot4(A4, xs4[lane + 256]) + dot4(A5, xs4[lane + 320]);
  float s3 = dot4(A6, xs4[lane + 384]) + dot4(A7, xs4[lane + 448]);
  float d = waveReduce((s0 + s1) + (s2 + s3));
  if (lane == 0) g_gpart[k][r] = d;
}

// ---------------- Stage 4: LSTM elementwise + output dot --------------------
__global__ __launch_bounds__(1024) void k_lstm(
    const float* __restrict__ c_in, const float* __restrict__ Wout,
    const float* __restrict__ bout, float* __restrict__ dout) {
  __shared__ float red[16];
  int j = threadIdx.x;
  float gv[4];
  #pragma unroll
  for (int g = 0; g < 4; ++g) {
    int idx = g * H + j;
    gv[g] = g_gates[idx] + ((g_gpart[0][idx] + g_gpart[1][idx]) +
                            (g_gpart[2][idx] + g_gpart[3][idx]));
  }
  float c = c_in[j];
  float cn = sigm(gv[1]) * c + sigm(gv[0]) * tanhf(gv[2]);
  float hn = sigm(gv[3]) * tanhf(cn);
  dout[1 + R_TOT + j] = hn;
  dout[1 + R_TOT + H + j] = cn;
  float w = Wout[j] * hn;
  w = waveReduce(w);
  int wave = j >> 6, lane = j & 63;
  if (lane == 0) red[wave] = w;
  __syncthreads();
  if (j == 0) {
    float t = 0.f;
    #pragma unroll
    for (int kk = 0; kk < 16; ++kk) t += red[kk];
    dout[0] = t + bout[0];
  }
}

extern "C" void kernel_launch(void* const* d_in, const int* in_sizes, int n_in,
                              void* d_out, int out_size, void* d_ws, size_t ws_size,
                              hipStream_t stream) {
  // Map inputs by element-count fingerprint (confirmed f32).
  const float *x = 0, *state = 0, *h = 0, *c = 0, *Win = 0, *Wcore = 0, *Wshell = 0,
              *Wfb = 0, *Wsc = 0, *Wfc = 0, *dopa = 0, *omega = 0, *gamma = 0,
              *Wih = 0, *Whh = 0, *bih = 0, *bhh = 0, *Wout = 0, *bout = 0;
  int n1 = 0, n1024 = 0, n8192 = 0, n4096 = 0;
  for (int i = 0; i < n_in; ++i) {
    const float* p = (const float*)d_in[i];
    switch (in_sizes[i]) {
      case 24157225: Wcore = p; break;            // CORE^2
      case 6036849:  Wshell = p; break;           // SHELL^2
      case 672400:   Wfb = p; break;              // FB^2
      case 12076155: Wsc = p; break;              // CORE*SHELL
      case 4030300:  Wfc = p; break;              // CORE*FB
      case 33554432: Wih = p; break;              // 4H*R
      case 4194304:  Whh = p; break;              // 4H*H
      case 1:    { if (n1 == 0) x = p; else if (n1 == 1) dopa = p; else bout = p; n1++; } break;
      case 1024: { if (n1024 == 0) h = p; else if (n1024 == 1) c = p; else Wout = p; n1024++; } break;
      case 8192: { if (n8192 == 0) state = p; else if (n8192 == 1) Win = p;
                   else if (n8192 == 2) omega = p; else gamma = p; n8192++; } break;
      case 4096: { if (n4096 == 0) bih = p; else bhh = p; n4096++; } break;
      default: break;
    }
  }
  float* dout = (float*)d_out;

  k_stage1<<<NB1_TOT, 256, 0, stream>>>(state, Wcore, Wshell, Wfb, Win, x,
                                        Whh, h, bih, bhh);
  k_stage2<<<NB2_CORE + NB2_EW, 256, 0, stream>>>(state, Wsc, Wfc, omega, gamma,
                                                  dopa, dout);
  k_gates<<<NBG, 256, 0, stream>>>(Wih);
  k_lstm<<<1, 1024, 0, stream>>>(c, Wout, bout, dout);
}